// Round 16
// baseline (94.561 us; speedup 1.0000x reference)
//
#include <hip/hip_runtime.h>

// DecoderLayer: out[k,n,m] = tanh(sum_p w[k,p]*prev[idx[k,p],n,m] + b[k]),
// gated by (#active parents >= 12).  M=2048, K=4096, NN=4096 (64x64), P=16.
//
// R16: occupancy attack. R12-R15 proved: instr count, width, prefetch all
// neutral at ~40us; every pipe ~40% duty; 16 waves/CU (LDS-pinned single
// block) can't cover the stall holes. Fix: POS_TILE=8, rows = 16B bf16
// + 8B pad = 24B (16 bank phases, 8B-align b64) -> LDS 48KiB -> TWO
// 1024-thread blocks/CU = 8 waves/SIMD. Grid 512 = exactly 2 blocks/CU.
// Lane-per-node: 2x ds_read_b64 covers the whole row. 32B/lane stores
// L2-merge to full lines via paired-tile XCD swizzle (proven R3).

#define M_ROWS   2048
#define K_NODES  4096
#define NN       4096
#define POS_TILE 8
#define NTHREADS 1024
#define ROW_B    24                          // bytes per padded bf16 row
#define LDS_BYTES (M_ROWS * ROW_B)           // 49152 = 48 KiB
#define OUT_ELEMS (K_NODES * NN)
#define ACTIVE_THRESHOLD 12

typedef float f32x4 __attribute__((ext_vector_type(4)));
typedef unsigned short u16x4 __attribute__((ext_vector_type(4)));

__device__ __forceinline__ float fast_tanh(float x) {
  float ax = __builtin_fabsf(x);
  float e  = __expf(-2.0f * ax);
  float r  = (1.0f - e) * __builtin_amdgcn_rcpf(1.0f + e);
  return __builtin_copysignf(r, x);
}

__device__ __forceinline__ unsigned short f2bf_rne(float f) {
  unsigned u = __float_as_uint(f);
  u += 0x7FFFu + ((u >> 16) & 1u);           // round-to-nearest-even
  return (unsigned short)(u >> 16);
}

// Gate precompute (off hot path). Runtime-detects isact marshaling:
// any 32-bit word >1 in the first 2048 bytes implies packed bytes.
__global__ __launch_bounds__(256) void act_kernel(
    const int* __restrict__ pidx, const unsigned int* __restrict__ isact,
    float* __restrict__ outact) {
  __shared__ int mode_sh;
  if (threadIdx.x == 0) mode_sh = 0;
  __syncthreads();
  int bad = 0;
  for (int i = threadIdx.x; i < 512; i += 256) bad |= (isact[i] > 1u);
  if (bad) atomicOr(&mode_sh, 1);
  __syncthreads();
  const int shift = mode_sh ? 0 : 2;   // LSB byte of a 0/1 int32 == its value
  const unsigned char* actb = (const unsigned char*)isact;

  int k = blockIdx.x * 256 + threadIdx.x;
  const int4* ip = (const int4*)(pidx + k * 16);
  int4 ia = ip[0], ib = ip[1], ic = ip[2], id4 = ip[3];
  int ids[16] = {ia.x, ia.y, ia.z, ia.w, ib.x, ib.y, ib.z, ib.w,
                 ic.x, ic.y, ic.z, ic.w, id4.x, id4.y, id4.z, id4.w};
  int n = 0;
  #pragma unroll
  for (int p = 0; p < 16; ++p) n += (actb[ids[p] << shift] != 0);
  outact[k] = (n >= ACTIVE_THRESHOLD) ? 1.0f : 0.0f;
}

// one parent: lo = positions 0-3, hi = positions 4-7
#define PFMA2(lo, hi, wv)                                          \
  { float wv_ = (wv);                                              \
    a0 += wv_ * __uint_as_float((unsigned)(lo)[0] << 16);          \
    a1 += wv_ * __uint_as_float((unsigned)(lo)[1] << 16);          \
    a2 += wv_ * __uint_as_float((unsigned)(lo)[2] << 16);          \
    a3 += wv_ * __uint_as_float((unsigned)(lo)[3] << 16);          \
    a4 += wv_ * __uint_as_float((unsigned)(hi)[0] << 16);          \
    a5 += wv_ * __uint_as_float((unsigned)(hi)[1] << 16);          \
    a6 += wv_ * __uint_as_float((unsigned)(hi)[2] << 16);          \
    a7 += wv_ * __uint_as_float((unsigned)(hi)[3] << 16); }

__global__ __launch_bounds__(NTHREADS, 8) void decoder_kernel(
    const float* __restrict__ prev, const int* __restrict__ pidx,
    const float* __restrict__ w, const float* __restrict__ b,
    const float* __restrict__ actf, float* __restrict__ out) {
  extern __shared__ char xb[];               // [2048 rows][24 B] bf16 tile
  const int tid = threadIdx.x;
  const int bid = blockIdx.x;                // 0..511

  // XCD swizzle: xcd = bid&7 (dispatch round-robin); each XCD owns 64
  // consecutive tiles -> tile pairs sharing a 64B out-line co-reside on
  // one XCD (L2 write-merge, proven R3), prev slice 4MB = its L2.
  const int xcd  = bid & 7;
  const int tile = xcd * 64 + (bid >> 3);    // 0..511
  const int pos0 = tile * POS_TILE;

  // ---- stage prev[:, pos0:pos0+8] as bf16-RNE into 24B padded rows ----
  #pragma unroll
  for (int it = 0; it < 2; ++it) {
    int r = (it << 10) + tid;                // row 0..2047
    const float* sp = prev + r * NN + pos0;  // 32B aligned
    f32x4 v0 = *(const f32x4*)sp;
    f32x4 v1 = *(const f32x4*)(sp + 4);
    u16x4 lo, hi;
    lo[0] = f2bf_rne(v0.x); lo[1] = f2bf_rne(v0.y);
    lo[2] = f2bf_rne(v0.z); lo[3] = f2bf_rne(v0.w);
    hi[0] = f2bf_rne(v1.x); hi[1] = f2bf_rne(v1.y);
    hi[2] = f2bf_rne(v1.z); hi[3] = f2bf_rne(v1.w);
    char* dp = xb + r * ROW_B;               // 8B aligned (24 = 3*8)
    *(u16x4*)dp       = lo;                  // ds_write_b64
    *(u16x4*)(dp + 8) = hi;                  // ds_write_b64
  }
  __syncthreads();

  for (int it = 0; it < 4; ++it) {           // 4096 nodes / 1024 threads
    int n = (it << 10) + tid;                // lane owns node n entirely
    const int4*   ip = (const int4*)(pidx + (n << 4));
    const float4* wp = (const float4*)(w + (n << 4));
    int4   i0 = ip[0], i1 = ip[1], i2 = ip[2], i3 = ip[3];
    float4 w0 = wp[0], w1 = wp[1], w2 = wp[2], w3 = wp[3];
    float  bk = b[n];
    float  g  = actf[n];                     // 0.0 / 1.0

    float a0 = bk, a1 = bk, a2 = bk, a3 = bk;
    float a4 = bk, a5 = bk, a6 = bk, a7 = bk;

    // batch 1: parents 0..3 — 8 independent ds_read_b64
    const char* r0 = xb + i0.x * ROW_B;
    const char* r1 = xb + i0.y * ROW_B;
    const char* r2 = xb + i0.z * ROW_B;
    const char* r3 = xb + i0.w * ROW_B;
    u16x4 l0 = *(const u16x4*)r0, h0 = *(const u16x4*)(r0 + 8);
    u16x4 l1 = *(const u16x4*)r1, h1 = *(const u16x4*)(r1 + 8);
    u16x4 l2 = *(const u16x4*)r2, h2 = *(const u16x4*)(r2 + 8);
    u16x4 l3 = *(const u16x4*)r3, h3 = *(const u16x4*)(r3 + 8);
    __builtin_amdgcn_sched_barrier(0);
    PFMA2(l0, h0, w0.x) PFMA2(l1, h1, w0.y)
    PFMA2(l2, h2, w0.z) PFMA2(l3, h3, w0.w)

    // batch 2: parents 4..7
    r0 = xb + i1.x * ROW_B;  r1 = xb + i1.y * ROW_B;
    r2 = xb + i1.z * ROW_B;  r3 = xb + i1.w * ROW_B;
    l0 = *(const u16x4*)r0;  h0 = *(const u16x4*)(r0 + 8);
    l1 = *(const u16x4*)r1;  h1 = *(const u16x4*)(r1 + 8);
    l2 = *(const u16x4*)r2;  h2 = *(const u16x4*)(r2 + 8);
    l3 = *(const u16x4*)r3;  h3 = *(const u16x4*)(r3 + 8);
    __builtin_amdgcn_sched_barrier(0);
    PFMA2(l0, h0, w1.x) PFMA2(l1, h1, w1.y)
    PFMA2(l2, h2, w1.z) PFMA2(l3, h3, w1.w)

    // batch 3: parents 8..11
    r0 = xb + i2.x * ROW_B;  r1 = xb + i2.y * ROW_B;
    r2 = xb + i2.z * ROW_B;  r3 = xb + i2.w * ROW_B;
    l0 = *(const u16x4*)r0;  h0 = *(const u16x4*)(r0 + 8);
    l1 = *(const u16x4*)r1;  h1 = *(const u16x4*)(r1 + 8);
    l2 = *(const u16x4*)r2;  h2 = *(const u16x4*)(r2 + 8);
    l3 = *(const u16x4*)r3;  h3 = *(const u16x4*)(r3 + 8);
    __builtin_amdgcn_sched_barrier(0);
    PFMA2(l0, h0, w2.x) PFMA2(l1, h1, w2.y)
    PFMA2(l2, h2, w2.z) PFMA2(l3, h3, w2.w)

    // batch 4: parents 12..15
    r0 = xb + i3.x * ROW_B;  r1 = xb + i3.y * ROW_B;
    r2 = xb + i3.z * ROW_B;  r3 = xb + i3.w * ROW_B;
    l0 = *(const u16x4*)r0;  h0 = *(const u16x4*)(r0 + 8);
    l1 = *(const u16x4*)r1;  h1 = *(const u16x4*)(r1 + 8);
    l2 = *(const u16x4*)r2;  h2 = *(const u16x4*)(r2 + 8);
    l3 = *(const u16x4*)r3;  h3 = *(const u16x4*)(r3 + 8);
    __builtin_amdgcn_sched_barrier(0);
    PFMA2(l0, h0, w3.x) PFMA2(l1, h1, w3.y)
    PFMA2(l2, h2, w3.z) PFMA2(l3, h3, w3.w)

    f32x4 o0, o1;
    o0.x = fast_tanh(a0) * g; o0.y = fast_tanh(a1) * g;
    o0.z = fast_tanh(a2) * g; o0.w = fast_tanh(a3) * g;
    o1.x = fast_tanh(a4) * g; o1.y = fast_tanh(a5) * g;
    o1.z = fast_tanh(a6) * g; o1.w = fast_tanh(a7) * g;

    // 32B store; neighbor tile (same XCD) writes the other half of the
    // 64B line -> L2 merges before HBM writeback (proven R3).
    float* op = out + ((size_t)n << 12) + pos0;
    *(f32x4*)op       = o0;
    *(f32x4*)(op + 4) = o1;
  }
}

extern "C" void kernel_launch(void* const* d_in, const int* in_sizes, int n_in,
                              void* d_out, int out_size, void* d_ws, size_t ws_size,
                              hipStream_t stream) {
  const float* prev  = (const float*)d_in[0];
  const void*  isact = d_in[1];
  const int*   pidx  = (const int*)d_in[2];
  const float* w     = (const float*)d_in[3];
  const float* b     = (const float*)d_in[4];
  float* out    = (float*)d_out;
  float* outact = out + OUT_ELEMS;           // act_kernel writes the gate vector

  (void)hipFuncSetAttribute((const void*)decoder_kernel,
                            hipFuncAttributeMaxDynamicSharedMemorySize, LDS_BYTES);

  act_kernel<<<K_NODES / 256, 256, 0, stream>>>(
      pidx, (const unsigned int*)isact, outact);
  decoder_kernel<<<NN / POS_TILE, NTHREADS, LDS_BYTES, stream>>>(
      prev, pidx, w, b, outact, out);
}

// Round 17
// 40.312 us; speedup vs baseline: 2.3458x; 2.3458x over previous
//
#include <hip/hip_runtime.h>

// DecoderLayer: out[k,n,m] = tanh(sum_p w[k,p]*prev[idx[k,p],n,m] + b[k]),
// gated by (#active parents >= 12).  M=2048, K=4096, NN=4096 (64x64), P=16.
//
// R17 = R13's layout with the occupancy experiment actually run:
//   - R16 lesson: 32B partial-line I/O caused HBM RMW (WRITE 207MB) ->
//     POS_TILE=16 so every block reads AND writes full 64B lines.
//   - R13 lesson re-read: grid was 256 = 1 block/CU; 2-blocks/CU was never
//     tested. Here: grid 512 = 256 tiles x 2 node-halves, 80KiB LDS ->
//     2 x 1024-thread blocks/CU = 32 waves/CU (2x R12-R15 coverage).
//   - 40B rows (16 phases at b64 granularity; R13 measured ~4cyc/instr
//     conflicts), lane-QUAD per node, 4x ds_read_b64 per parent-batch.

#define M_ROWS   2048
#define K_NODES  4096
#define NN       4096
#define POS_TILE 16
#define NTHREADS 1024
#define ROW_B    40                          // bytes per padded bf16 row
#define LDS_BYTES (M_ROWS * ROW_B)           // 81920 = 80 KiB -> 2 blocks/CU
#define OUT_ELEMS (K_NODES * NN)
#define ACTIVE_THRESHOLD 12

typedef float f32x4 __attribute__((ext_vector_type(4)));
typedef unsigned short u16x4 __attribute__((ext_vector_type(4)));

__device__ __forceinline__ float fast_tanh(float x) {
  float ax = __builtin_fabsf(x);
  float e  = __expf(-2.0f * ax);
  float r  = (1.0f - e) * __builtin_amdgcn_rcpf(1.0f + e);
  return __builtin_copysignf(r, x);
}

__device__ __forceinline__ unsigned short f2bf_rne(float f) {
  unsigned u = __float_as_uint(f);
  u += 0x7FFFu + ((u >> 16) & 1u);           // round-to-nearest-even
  return (unsigned short)(u >> 16);
}

// Gate precompute (off hot path). Runtime-detects isact marshaling:
// any 32-bit word >1 in the first 2048 bytes implies packed bytes.
__global__ __launch_bounds__(256) void act_kernel(
    const int* __restrict__ pidx, const unsigned int* __restrict__ isact,
    float* __restrict__ outact) {
  __shared__ int mode_sh;
  if (threadIdx.x == 0) mode_sh = 0;
  __syncthreads();
  int bad = 0;
  for (int i = threadIdx.x; i < 512; i += 256) bad |= (isact[i] > 1u);
  if (bad) atomicOr(&mode_sh, 1);
  __syncthreads();
  const int shift = mode_sh ? 0 : 2;   // LSB byte of a 0/1 int32 == its value
  const unsigned char* actb = (const unsigned char*)isact;

  int k = blockIdx.x * 256 + threadIdx.x;
  const int4* ip = (const int4*)(pidx + k * 16);
  int4 ia = ip[0], ib = ip[1], ic = ip[2], id4 = ip[3];
  int ids[16] = {ia.x, ia.y, ia.z, ia.w, ib.x, ib.y, ib.z, ib.w,
                 ic.x, ic.y, ic.z, ic.w, id4.x, id4.y, id4.z, id4.w};
  int n = 0;
  #pragma unroll
  for (int p = 0; p < 16; ++p) n += (actb[ids[p] << shift] != 0);
  outact[k] = (n >= ACTIVE_THRESHOLD) ? 1.0f : 0.0f;
}

// unpack-and-FMA one parent chunk: 4 bf16 positions into 4 scalar f32 accs
#define PFMA4(vv, wv)                                             \
  { float wv_ = (wv);                                             \
    a0 += wv_ * __uint_as_float((unsigned)(vv)[0] << 16);         \
    a1 += wv_ * __uint_as_float((unsigned)(vv)[1] << 16);         \
    a2 += wv_ * __uint_as_float((unsigned)(vv)[2] << 16);         \
    a3 += wv_ * __uint_as_float((unsigned)(vv)[3] << 16); }

__global__ __launch_bounds__(NTHREADS, 8) void decoder_kernel(
    const float* __restrict__ prev, const int* __restrict__ pidx,
    const float* __restrict__ w, const float* __restrict__ b,
    const float* __restrict__ actf, float* __restrict__ out) {
  extern __shared__ char xb[];               // [2048 rows][40 B] bf16 tile
  const int tid = threadIdx.x;
  const int bid = blockIdx.x;                // 0..511

  // XCD co-location: xcd = bid&7 (dispatch round-robin). Each XCD owns 32
  // tiles; a tile's two node-half blocks land on the same XCD -> the
  // second block's staging reads hit L2/L3 (proven R11/R12).
  const int xcd   = bid & 7;
  const int j     = bid >> 3;                // 0..63
  const int tile  = xcd * 32 + (j >> 1);     // 0..255
  const int half  = j & 1;
  const int pos0  = tile * POS_TILE;
  const int nbase = half * (K_NODES / 2);

  // ---- stage prev[:, pos0:pos0+16] as bf16-RNE into 40B padded rows ----
  // full 64B-line reads; thread handles (row r, chunk c of 4 f32)
  #pragma unroll
  for (int it = 0; it < 8; ++it) {
    int ci = (it << 10) + tid;               // 0..8191
    int r = ci >> 2, c = ci & 3;
    f32x4 v = *(const f32x4*)(prev + r * NN + pos0 + (c << 2));
    u16x4 o;
    o[0] = f2bf_rne(v.x); o[1] = f2bf_rne(v.y);
    o[2] = f2bf_rne(v.z); o[3] = f2bf_rne(v.w);
    *(u16x4*)(xb + r * ROW_B + (c << 3)) = o;   // ds_write_b64, 8B aligned
  }
  __syncthreads();

  const int q  = tid & 3;                    // chunk (4 positions) this lane owns
  const int s  = tid >> 2;                   // node slot 0..255
  const int qb = q << 3;                     // byte offset within row

  for (int it = 0; it < 8; ++it) {           // 2048 nodes / 256 slots
    int n = nbase + (it << 8) + s;
    const int4*   ip = (const int4*)(pidx + (n << 4));
    const float4* wp = (const float4*)(w + (n << 4));
    float bk = b[n];
    float g  = actf[n];                      // 0.0 / 1.0

    float a0 = bk, a1 = bk, a2 = bk, a3 = bk;

    #pragma unroll
    for (int bb = 0; bb < 4; ++bb) {         // 4 batches of 4 parents
      int4   iv = ip[bb];
      float4 wv = wp[bb];
      // 4 independent ds_read_b64 (quad covers the row's 32B)
      u16x4 v0 = *(const u16x4*)(xb + iv.x * ROW_B + qb);
      u16x4 v1 = *(const u16x4*)(xb + iv.y * ROW_B + qb);
      u16x4 v2 = *(const u16x4*)(xb + iv.z * ROW_B + qb);
      u16x4 v3 = *(const u16x4*)(xb + iv.w * ROW_B + qb);
      __builtin_amdgcn_sched_barrier(0);     // keep 4 reads in flight
      PFMA4(v0, wv.x) PFMA4(v1, wv.y) PFMA4(v2, wv.z) PFMA4(v3, wv.w)
    }

    f32x4 o;
    o.x = fast_tanh(a0) * g;
    o.y = fast_tanh(a1) * g;
    o.z = fast_tanh(a2) * g;
    o.w = fast_tanh(a3) * g;
    // quad writes node n's full 64B line
    *(f32x4*)(out + ((size_t)n << 12) + pos0 + (q << 2)) = o;
  }
}

extern "C" void kernel_launch(void* const* d_in, const int* in_sizes, int n_in,
                              void* d_out, int out_size, void* d_ws, size_t ws_size,
                              hipStream_t stream) {
  const float* prev  = (const float*)d_in[0];
  const void*  isact = d_in[1];
  const int*   pidx  = (const int*)d_in[2];
  const float* w     = (const float*)d_in[3];
  const float* b     = (const float*)d_in[4];
  float* out    = (float*)d_out;
  float* outact = out + OUT_ELEMS;           // act_kernel writes the gate vector

  (void)hipFuncSetAttribute((const void*)decoder_kernel,
                            hipFuncAttributeMaxDynamicSharedMemorySize, LDS_BYTES);

  act_kernel<<<K_NODES / 256, 256, 0, stream>>>(
      pidx, (const unsigned int*)isact, outact);
  decoder_kernel<<<(NN / POS_TILE) * 2, NTHREADS, LDS_BYTES, stream>>>(
      prev, pidx, w, b, outact, out);
}